// Round 8
// baseline (252.356 us; speedup 1.0000x reference)
//
#include <hip/hip_runtime.h>
#include <hip/hip_fp16.h>
#include <hip/hip_bf16.h>
#include <stdint.h>

#define WN 343       // tokens per window
#define NH 6         // heads
#define HD 32        // head dim
#define CD 192       // channels
#define NB 128       // windows (batch)
#define NWM 32       // mask windows
#define BMROW 352            // padded query dim
#define BMSLICE (11*16*BMROW) // dwords per slice = 61952

typedef __attribute__((ext_vector_type(8))) short short8;
typedef __attribute__((ext_vector_type(4))) float f32x4;

__device__ __forceinline__ unsigned short f2bf(float f) {
  union { float f; uint32_t u; } v; v.f = f;
  uint32_t r = v.u + 0x7fffu + ((v.u >> 16) & 1u);
  return (unsigned short)(r >> 16);
}

// packed f32x2 -> bf16x2 (v_cvt_pk_bf16_f32 on gfx950); low half = a
__device__ __forceinline__ uint32_t pk2bf(float a, float b) {
  __hip_bfloat162 h = __float22bfloat162_rn(make_float2(a, b));
  return *(uint32_t*)&h;
}

// ---------------- prep: bias repack (66) | mask repack (352) | w cvt (144)
// biasP[h][kc][rr][n] / maskP[wdx][kc][rr][n]: fp16x2 for keys
// kA=kc*32+(rr>>2)*8+(rr&3), kA+4. OOB keys: bias=-60000, mask=0.
__global__ __launch_bounds__(256) void prep_kernel(
    const float* __restrict__ wq, const float* __restrict__ wp,
    unsigned short* __restrict__ wqb, unsigned short* __restrict__ wpb,
    const int* __restrict__ rel, const float* __restrict__ rpb,
    const float* __restrict__ mask, uint32_t* __restrict__ bP,
    uint32_t* __restrict__ mP) {
  __shared__ float M[352][33];
  const int bid = blockIdx.x;
  if (bid < 66 + 352) {
    const bool isBias = (bid < 66);
    const int sub = isBias ? bid : bid - 66;
    const int grp = sub / 11;          // h or wdx
    const int kc = sub - grp * 11;
    const int k0 = kc * 32;
    const float* mw = mask + (size_t)grp * (WN * WN);
    for (int idx = threadIdx.x; idx < 352 * 32; idx += 256) {
      int n = idx >> 5, k = idx & 31;
      float v;
      if (isBias) {
        int nc = (n < WN) ? n : (WN - 1);
        v = (k0 + k < WN) ? rpb[rel[nc * WN + k0 + k] * NH + grp] : -60000.0f;
      } else {
        v = (n < WN && k0 + k < WN) ? mw[n * WN + k0 + k] : 0.0f;
      }
      M[n][k] = v;
    }
    __syncthreads();
    uint32_t* outp = (isBias ? bP : mP) + (size_t)grp * BMSLICE + kc * 16 * BMROW;
#pragma unroll
    for (int rr = 0; rr < 16; ++rr) {
      int kkA = (rr >> 2) * 8 + (rr & 3);
#pragma unroll
      for (int j = 0; j < 2; ++j) {
        int n = threadIdx.x + 256 * j;
        if (n < 352) {
          __half2 hv; hv.x = __float2half(M[n][kkA]); hv.y = __float2half(M[n][kkA + 4]);
          outp[rr * BMROW + n] = *(uint32_t*)&hv;
        }
      }
    }
    return;
  }
  // ---- cvt branch: fp32 -> bf16 (qkv_w, proj_w)
  const int NWQ = 3 * CD * CD;     // 110,592
  const int NWP = CD * CD;         // 36,864
  int i4 = ((bid - 418) * 256 + threadIdx.x) * 4;
  const float* src; unsigned short* dst; int off;
  if (i4 < NWQ) { src = wq; dst = wqb; off = i4; }
  else if (i4 < NWQ + NWP) { src = wp; dst = wpb; off = i4 - NWQ; }
  else return;
  f32x4 v = *(const f32x4*)(src + off);
  union { uint2 u2; uint32_t d[2]; } o;
  o.d[0] = pk2bf(v[0], v[1]);
  o.d[1] = pk2bf(v[2], v[3]);
  *(uint2*)(dst + off) = o.u2;
}

// ---------------- QKV GEMM: 128x192 tiles; x fp32 in (converted at staging),
// bf16 out via LDS-repacked coalesced stores.
__global__ __launch_bounds__(256) void qkv_kernel(
    const float* __restrict__ x, const unsigned short* __restrict__ wqb,
    const float* __restrict__ bvec,
    unsigned short* __restrict__ qb, unsigned short* __restrict__ kb,
    unsigned short* __restrict__ vb) {
  __shared__ __align__(16) unsigned short Xs[128][40];
  __shared__ __align__(16) unsigned short Ws[192][40];
  __shared__ __align__(16) unsigned short Lh[2][128][40];  // epilogue repack
  const int tid = threadIdx.x;
  const int wave = tid >> 6, lane = tid & 63;
  const int quad = lane >> 4, c = lane & 15;
  const int m0 = blockIdx.x * 128;
  const int s = blockIdx.y;            // 0=q, 1=k, 2=v
  const int n0 = s * 192;

  f32x4 acc[2][12];
#pragma unroll
  for (int i = 0; i < 2; ++i)
#pragma unroll
    for (int j = 0; j < 12; ++j) acc[i][j] = (f32x4){0.f, 0.f, 0.f, 0.f};

  for (int kt = 0; kt < 6; ++kt) {
    const int k0 = kt * 32;
#pragma unroll
    for (int it = 0; it < 2; ++it) {
      int tq = tid + it * 256;
      int r = tq >> 2, ch = tq & 3;
      const float* src = x + (size_t)(m0 + r) * CD + k0 + ch * 8;
      f32x4 a = *(const f32x4*)src;
      f32x4 b = *(const f32x4*)(src + 4);
      union { short8 v8; uint32_t d[4]; } pk;
      pk.d[0] = pk2bf(a[0], a[1]);
      pk.d[1] = pk2bf(a[2], a[3]);
      pk.d[2] = pk2bf(b[0], b[1]);
      pk.d[3] = pk2bf(b[2], b[3]);
      *(short8*)&Xs[r][ch * 8] = pk.v8;
    }
#pragma unroll
    for (int it = 0; it < 3; ++it) {
      int r = it * 64 + (tid >> 2), ch = tid & 3;
      *(short8*)&Ws[r][ch * 8] =
          *(const short8*)(wqb + (size_t)(n0 + r) * CD + k0 + ch * 8);
    }
    __syncthreads();
    short8 af0 = *(const short8*)&Xs[wave * 32 + c][quad * 8];
    short8 af1 = *(const short8*)&Xs[wave * 32 + 16 + c][quad * 8];
#pragma unroll
    for (int j = 0; j < 12; ++j) {
      short8 bfr = *(const short8*)&Ws[j * 16 + c][quad * 8];
      acc[0][j] = __builtin_amdgcn_mfma_f32_16x16x32_bf16(af0, bfr, acc[0][j], 0, 0, 0);
      acc[1][j] = __builtin_amdgcn_mfma_f32_16x16x32_bf16(af1, bfr, acc[1][j], 0, 0, 0);
    }
    __syncthreads();
  }

  const float qscale = 0.17677669529663689f;  // 32^-0.5
  unsigned short* dst = (s == 0) ? qb : ((s == 1) ? kb : vb);
  const float scl = (s == 0) ? qscale : 1.0f;
  // epilogue: repack per head-pair through LDS, store coalesced short8
  for (int hh = 0; hh < 3; ++hh) {
    __syncthreads();
#pragma unroll
    for (int jj = 0; jj < 4; ++jj) {
      int j = hh * 4 + jj;
      int hl = jj >> 1;
      int dd = (jj & 1) * 16 + c;
      float bn = bvec[n0 + j * 16 + c];
#pragma unroll
      for (int i = 0; i < 2; ++i)
#pragma unroll
        for (int r = 0; r < 4; ++r) {
          int m = wave * 32 + i * 16 + quad * 4 + r;
          Lh[hl][m][dd] = f2bf((acc[i][j][r] + bn) * scl);
        }
    }
    __syncthreads();
    const int m = tid & 127;
    const int hl = tid >> 7;
    const int M = m0 + m;
    const int b = M / WN;
    const int tok = M - b * WN;
    const int h = hh * 2 + hl;
    unsigned short* drow = dst + (((size_t)b * NH + h) * WN + tok) * HD;
#pragma unroll
    for (int t2 = 0; t2 < 4; ++t2) {
      int d0 = t2 * 8;
      *(short8*)&drow[d0] = *(const short8*)&Lh[hl][m][d0];
    }
  }
}

// ---------------- fused attention: single streaming loop, no softmax max-sub
// Key rows permuted at staging (key kk=8q+4e+r -> LDS row 16e+4q+r); lane
// (c,quad) holds scores for query q0+c, keys quad*8+{0..7} = the PV A-frag.
// bias+mask enters as the QK^T MFMA C-operand. exp unnormalized; 1/l in
// epilogue. NOTE: plain __launch_bounds__(256) — a min-waves arg makes the
// allocator cap VGPRs and spill (r5: +29MB scratch traffic).
__global__ __launch_bounds__(256) void attn_kernel(
    const unsigned short* __restrict__ qb, const unsigned short* __restrict__ kb,
    const unsigned short* __restrict__ vb, const uint32_t* __restrict__ biasP,
    const uint32_t* __restrict__ maskP, unsigned short* __restrict__ ob) {
  __shared__ __align__(16) unsigned short Ks[352][40];  // [perm key row][d]
  __shared__ __align__(16) unsigned short Vt[HD][360];  // [d][key]
  const int h = blockIdx.x, b = blockIdx.y;
  const int wdx = b & (NWM - 1);
  const int tid = threadIdx.x;
  const int wave = tid >> 6, lane = tid & 63;
  const int quad = lane >> 4, c = lane & 15;
  const size_t base = ((size_t)b * NH + h) * (WN * HD);
  const unsigned short* q = qb + base;
  const unsigned short* k = kb + base;
  const unsigned short* v = vb + base;
  const uint32_t* bP = biasP + (size_t)h * BMSLICE;
  const uint32_t* mP = maskP + (size_t)wdx * BMSLICE;

  // stage K with permuted rows
  for (int t = tid; t < WN * 4; t += 256) {
    int r = t >> 2, ch = t & 3;
    int kk = r & 31;
    int row = (r & ~31) + 16 * ((kk >> 2) & 1) + 4 * (kk >> 3) + (kk & 3);
    *(short8*)&Ks[row][ch * 8] = *(const short8*)(k + r * HD + ch * 8);
  }
  for (int t = tid; t < 9 * 32; t += 256) {
    int kg = WN + (t >> 5);
    int kk = kg & 31;
    int row = (kg & ~31) + 16 * ((kk >> 2) & 1) + 4 * (kk >> 3) + (kk & 3);
    Ks[row][t & 31] = 0;
  }
  // stage V transposed, natural key order
  for (int t = tid; t < WN; t += 256) {
#pragma unroll
    for (int ch = 0; ch < 4; ++ch) {
      short8 vv = *(const short8*)(v + t * HD + ch * 8);
#pragma unroll
      for (int j = 0; j < 8; ++j) Vt[ch * 8 + j][t] = vv[j];
    }
  }
  for (int t = tid; t < 9 * 32; t += 256) {
    Vt[t & 31][WN + (t >> 5)] = 0;
  }
  __syncthreads();

  for (int qt = wave; qt < 22; qt += 4) {
    const int q0 = qt * 16;
    int qr = q0 + c; if (qr > WN - 1) qr = WN - 1;
    const short8 qf = *(const short8*)(q + qr * HD + quad * 8);
    const uint32_t* bRow = bP + (size_t)(quad * 4) * BMROW + q0 + c;
    const uint32_t* mRow = mP + (size_t)(quad * 4) * BMROW + q0 + c;

    f32x4 o0 = (f32x4){0.f, 0.f, 0.f, 0.f}, o1 = (f32x4){0.f, 0.f, 0.f, 0.f};
    float l = 0.f;
#pragma unroll
    for (int kc = 0; kc < 11; ++kc) {
      // C-operand = bias+mask for this lane's 8 keys
      f32x4 cc0, cc1;
#pragma unroll
      for (int r = 0; r < 4; ++r) {
        uint32_t bw = bRow[(kc * 16 + r) * BMROW];
        uint32_t mw = mRow[(kc * 16 + r) * BMROW];
        __half2 s2 = __hadd2(*(__half2*)&bw, *(__half2*)&mw);
        float2 f = __half22float2(s2);
        cc0[r] = f.x;
        cc1[r] = f.y;
      }
      const int k0 = kc * 32;
      short8 kf0 = *(const short8*)&Ks[k0 + c][quad * 8];
      short8 kf1 = *(const short8*)&Ks[k0 + 16 + c][quad * 8];
      f32x4 s0 = __builtin_amdgcn_mfma_f32_16x16x32_bf16(kf0, qf, cc0, 0, 0, 0);
      f32x4 s1 = __builtin_amdgcn_mfma_f32_16x16x32_bf16(kf1, qf, cc1, 0, 0, 0);
      // unnormalized exp (OOB keys carry -60000 -> exp==0)
      float p0 = __expf(s0[0]), p1 = __expf(s0[1]);
      float p2 = __expf(s0[2]), p3 = __expf(s0[3]);
      float p4 = __expf(s1[0]), p5 = __expf(s1[1]);
      float p6 = __expf(s1[2]), p7 = __expf(s1[3]);
      l += (p0 + p1 + p2 + p3) + (p4 + p5 + p6 + p7);
      union { short8 v8; uint32_t d[4]; } pf;
      pf.d[0] = pk2bf(p0, p1);
      pf.d[1] = pk2bf(p2, p3);
      pf.d[2] = pk2bf(p4, p5);
      pf.d[3] = pk2bf(p6, p7);
      short8 vf0 = *(const short8*)&Vt[c][k0 + quad * 8];
      short8 vf1 = *(const short8*)&Vt[16 + c][k0 + quad * 8];
      o0 = __builtin_amdgcn_mfma_f32_16x16x32_bf16(pf.v8, vf0, o0, 0, 0, 0);
      o1 = __builtin_amdgcn_mfma_f32_16x16x32_bf16(pf.v8, vf1, o1, 0, 0, 0);
    }
    l += __shfl_xor(l, 16);
    l += __shfl_xor(l, 32);

    // Epilogue: O rows m=quad*4+r are queries q0+m; l lives at lane c=m
#pragma unroll
    for (int r = 0; r < 4; ++r) {
      int n = q0 + quad * 4 + r;
      if (n < WN) {
        float lq = __shfl(l, quad * 4 + r, 16);
        float inv = 1.0f / lq;
        size_t orow = ((size_t)b * WN + n) * CD + h * HD;
        ob[orow + c] = f2bf(o0[r] * inv);
        ob[orow + 16 + c] = f2bf(o1[r] * inv);
      }
    }
  }
}

// ---------------- output projection: 128x192 tile, fp32 out
__global__ __launch_bounds__(256) void proj_kernel(
    const unsigned short* __restrict__ ob, const unsigned short* __restrict__ wpb,
    const float* __restrict__ bvec, float* __restrict__ out) {
  __shared__ __align__(16) unsigned short Xs[128][40];
  __shared__ __align__(16) unsigned short Ws[192][40];
  const int tid = threadIdx.x;
  const int wave = tid >> 6, lane = tid & 63;
  const int quad = lane >> 4, c = lane & 15;
  const int m0 = blockIdx.x * 128;

  f32x4 acc[2][12];
#pragma unroll
  for (int i = 0; i < 2; ++i)
#pragma unroll
    for (int j = 0; j < 12; ++j) acc[i][j] = (f32x4){0.f, 0.f, 0.f, 0.f};

  for (int kt = 0; kt < 6; ++kt) {
    const int k0 = kt * 32;
#pragma unroll
    for (int it = 0; it < 2; ++it) {
      int tq = tid + it * 256;
      int r = tq >> 2, ch = tq & 3;
      *(short8*)&Xs[r][ch * 8] =
          *(const short8*)(ob + (size_t)(m0 + r) * CD + k0 + ch * 8);
    }
#pragma unroll
    for (int it = 0; it < 3; ++it) {
      int r = it * 64 + (tid >> 2), ch = tid & 3;
      *(short8*)&Ws[r][ch * 8] =
          *(const short8*)(wpb + (size_t)r * CD + k0 + ch * 8);
    }
    __syncthreads();
    short8 af0 = *(const short8*)&Xs[wave * 32 + c][quad * 8];
    short8 af1 = *(const short8*)&Xs[wave * 32 + 16 + c][quad * 8];
#pragma unroll
    for (int j = 0; j < 12; ++j) {
      short8 bfr = *(const short8*)&Ws[j * 16 + c][quad * 8];
      acc[0][j] = __builtin_amdgcn_mfma_f32_16x16x32_bf16(af0, bfr, acc[0][j], 0, 0, 0);
      acc[1][j] = __builtin_amdgcn_mfma_f32_16x16x32_bf16(af1, bfr, acc[1][j], 0, 0, 0);
    }
    __syncthreads();
  }

#pragma unroll
  for (int j = 0; j < 12; ++j) {
    int col = j * 16 + c;
    float bn = bvec[col];
#pragma unroll
    for (int i = 0; i < 2; ++i) {
#pragma unroll
      for (int r = 0; r < 4; ++r) {
        int m = m0 + wave * 32 + i * 16 + quad * 4 + r;
        out[(size_t)m * CD + col] = acc[i][j][r] + bn;
      }
    }
  }
}

extern "C" void kernel_launch(void* const* d_in, const int* in_sizes, int n_in,
                              void* d_out, int out_size, void* d_ws, size_t ws_size,
                              hipStream_t stream) {
  const float* x      = (const float*)d_in[0];
  const float* mask   = (const float*)d_in[1];
  const float* qkv_w  = (const float*)d_in[2];
  const float* qkv_b  = (const float*)d_in[3];
  const float* proj_w = (const float*)d_in[4];
  const float* proj_b = (const float*)d_in[5];
  const float* rpb    = (const float*)d_in[6];
  const int*   rel    = (const int*)d_in[7];
  float* out = (float*)d_out;

  char* ws = (char*)d_ws;
  uint32_t* biasP = (uint32_t*)ws;                       // 6*61952*4  = 1,486,848
  size_t off = 1486848;
  uint32_t* maskP = (uint32_t*)(ws + off); off += 7929856;  // 32*61952*4
  unsigned short* qb = (unsigned short*)(ws + off); off += 16859136;
  unsigned short* kb = (unsigned short*)(ws + off); off += 16859136;
  unsigned short* vb = (unsigned short*)(ws + off); off += 16859136;
  unsigned short* obuf = (unsigned short*)(ws + off); off += 16859136;
  unsigned short* wqb = (unsigned short*)(ws + off); off += 221184;
  unsigned short* wpb = (unsigned short*)(ws + off); off += 73728;

  hipLaunchKernelGGL(prep_kernel, dim3(418 + 144), dim3(256), 0, stream,
                     qkv_w, proj_w, wqb, wpb, rel, rpb, mask, biasP, maskP);
  hipLaunchKernelGGL(qkv_kernel, dim3(343, 3), dim3(256), 0, stream,
                     x, wqb, qkv_b, qb, kb, vb);
  hipLaunchKernelGGL(attn_kernel, dim3(NH, NB), dim3(256), 0, stream,
                     qb, kb, vb, biasP, maskP, obuf);
  hipLaunchKernelGGL(proj_kernel, dim3(343), dim3(256), 0, stream,
                     obuf, wpb, proj_b, out);
}

// Round 9
// 225.151 us; speedup vs baseline: 1.1208x; 1.1208x over previous
//
#include <hip/hip_runtime.h>
#include <hip/hip_fp16.h>
#include <hip/hip_bf16.h>
#include <stdint.h>

#define WN 343       // tokens per window
#define NH 6         // heads
#define HD 32        // head dim
#define CD 192       // channels
#define NB 128       // windows (batch)
#define NWM 32       // mask windows
#define BMROW 352            // padded query dim
#define BMSLICE (11*16*BMROW) // dwords per slice = 61952

typedef __attribute__((ext_vector_type(8))) short short8;
typedef __attribute__((ext_vector_type(4))) float f32x4;

__device__ __forceinline__ unsigned short f2bf(float f) {
  union { float f; uint32_t u; } v; v.f = f;
  uint32_t r = v.u + 0x7fffu + ((v.u >> 16) & 1u);
  return (unsigned short)(r >> 16);
}

// packed f32x2 -> bf16x2 (v_cvt_pk_bf16_f32 on gfx950); low half = a
__device__ __forceinline__ uint32_t pk2bf(float a, float b) {
  __hip_bfloat162 h = __float22bfloat162_rn(make_float2(a, b));
  return *(uint32_t*)&h;
}

// ---------------- prep: bias repack (66) | mask repack (352) | w cvt (144)
// biasP[h][kc][rr][n] / maskP[wdx][kc][rr][n]: fp16x2 for keys
// kA=kc*32+(rr>>2)*8+(rr&3), kA+4. OOB keys: bias=-60000, mask=0.
__global__ __launch_bounds__(256) void prep_kernel(
    const float* __restrict__ wq, const float* __restrict__ wp,
    unsigned short* __restrict__ wqb, unsigned short* __restrict__ wpb,
    const int* __restrict__ rel, const float* __restrict__ rpb,
    const float* __restrict__ mask, uint32_t* __restrict__ bP,
    uint32_t* __restrict__ mP) {
  __shared__ float M[352][33];
  const int bid = blockIdx.x;
  if (bid < 66 + 352) {
    const bool isBias = (bid < 66);
    const int sub = isBias ? bid : bid - 66;
    const int grp = sub / 11;          // h or wdx
    const int kc = sub - grp * 11;
    const int k0 = kc * 32;
    const float* mw = mask + (size_t)grp * (WN * WN);
    for (int idx = threadIdx.x; idx < 352 * 32; idx += 256) {
      int n = idx >> 5, k = idx & 31;
      float v;
      if (isBias) {
        int nc = (n < WN) ? n : (WN - 1);
        v = (k0 + k < WN) ? rpb[rel[nc * WN + k0 + k] * NH + grp] : -60000.0f;
      } else {
        v = (n < WN && k0 + k < WN) ? mw[n * WN + k0 + k] : 0.0f;
      }
      M[n][k] = v;
    }
    __syncthreads();
    uint32_t* outp = (isBias ? bP : mP) + (size_t)grp * BMSLICE + kc * 16 * BMROW;
#pragma unroll
    for (int rr = 0; rr < 16; ++rr) {
      int kkA = (rr >> 2) * 8 + (rr & 3);
#pragma unroll
      for (int j = 0; j < 2; ++j) {
        int n = threadIdx.x + 256 * j;
        if (n < 352) {
          __half2 hv; hv.x = __float2half(M[n][kkA]); hv.y = __float2half(M[n][kkA + 4]);
          outp[rr * BMROW + n] = *(uint32_t*)&hv;
        }
      }
    }
    return;
  }
  // ---- cvt branch: fp32 -> bf16 (qkv_w, proj_w)
  const int NWQ = 3 * CD * CD;     // 110,592
  const int NWP = CD * CD;         // 36,864
  int i4 = ((bid - 418) * 256 + threadIdx.x) * 4;
  const float* src; unsigned short* dst; int off;
  if (i4 < NWQ) { src = wq; dst = wqb; off = i4; }
  else if (i4 < NWQ + NWP) { src = wp; dst = wpb; off = i4 - NWQ; }
  else return;
  f32x4 v = *(const f32x4*)(src + off);
  union { uint2 u2; uint32_t d[2]; } o;
  o.d[0] = pk2bf(v[0], v[1]);
  o.d[1] = pk2bf(v[2], v[3]);
  *(uint2*)(dst + off) = o.u2;
}

// ---------------- QKV GEMM: 128x192 tiles; x fp32 in (converted at staging),
// bf16 out via LDS-repacked coalesced stores. Epilogue repack buffer OVERLAYS
// the dead Xs/Ws staging LDS (r8 lesson: a separate Lh buffer raised LDS to
// 46KB and cut blocks/CU 5->3, a net loss).
__global__ __launch_bounds__(256) void qkv_kernel(
    const float* __restrict__ x, const unsigned short* __restrict__ wqb,
    const float* __restrict__ bvec,
    unsigned short* __restrict__ qb, unsigned short* __restrict__ kb,
    unsigned short* __restrict__ vb) {
  __shared__ __align__(16) unsigned short Xs[128][40];
  __shared__ __align__(16) unsigned short Ws[192][40];
  const int tid = threadIdx.x;
  const int wave = tid >> 6, lane = tid & 63;
  const int quad = lane >> 4, c = lane & 15;
  const int m0 = blockIdx.x * 128;
  const int s = blockIdx.y;            // 0=q, 1=k, 2=v
  const int n0 = s * 192;

  f32x4 acc[2][12];
#pragma unroll
  for (int i = 0; i < 2; ++i)
#pragma unroll
    for (int j = 0; j < 12; ++j) acc[i][j] = (f32x4){0.f, 0.f, 0.f, 0.f};

  for (int kt = 0; kt < 6; ++kt) {
    const int k0 = kt * 32;
#pragma unroll
    for (int it = 0; it < 2; ++it) {
      int tq = tid + it * 256;
      int r = tq >> 2, ch = tq & 3;
      const float* src = x + (size_t)(m0 + r) * CD + k0 + ch * 8;
      f32x4 a = *(const f32x4*)src;
      f32x4 b = *(const f32x4*)(src + 4);
      union { short8 v8; uint32_t d[4]; } pk;
      pk.d[0] = pk2bf(a[0], a[1]);
      pk.d[1] = pk2bf(a[2], a[3]);
      pk.d[2] = pk2bf(b[0], b[1]);
      pk.d[3] = pk2bf(b[2], b[3]);
      *(short8*)&Xs[r][ch * 8] = pk.v8;
    }
#pragma unroll
    for (int it = 0; it < 3; ++it) {
      int r = it * 64 + (tid >> 2), ch = tid & 3;
      *(short8*)&Ws[r][ch * 8] =
          *(const short8*)(wqb + (size_t)(n0 + r) * CD + k0 + ch * 8);
    }
    __syncthreads();
    short8 af0 = *(const short8*)&Xs[wave * 32 + c][quad * 8];
    short8 af1 = *(const short8*)&Xs[wave * 32 + 16 + c][quad * 8];
#pragma unroll
    for (int j = 0; j < 12; ++j) {
      short8 bfr = *(const short8*)&Ws[j * 16 + c][quad * 8];
      acc[0][j] = __builtin_amdgcn_mfma_f32_16x16x32_bf16(af0, bfr, acc[0][j], 0, 0, 0);
      acc[1][j] = __builtin_amdgcn_mfma_f32_16x16x32_bf16(af1, bfr, acc[1][j], 0, 0, 0);
    }
    __syncthreads();
  }

  const float qscale = 0.17677669529663689f;  // 32^-0.5
  unsigned short* dst = (s == 0) ? qb : ((s == 1) ? kb : vb);
  const float scl = (s == 0) ? qscale : 1.0f;
  // epilogue repack buffers overlay dead staging LDS (barriers order access)
  unsigned short (*Lh0)[40] = (unsigned short (*)[40])&Xs[0][0];
  unsigned short (*Lh1)[40] = (unsigned short (*)[40])&Ws[0][0];
  for (int hh = 0; hh < 3; ++hh) {
    __syncthreads();
#pragma unroll
    for (int jj = 0; jj < 4; ++jj) {
      int j = hh * 4 + jj;
      int hl = jj >> 1;
      int dd = (jj & 1) * 16 + c;
      float bn = bvec[n0 + j * 16 + c];
      unsigned short (*L)[40] = hl ? Lh1 : Lh0;
#pragma unroll
      for (int i = 0; i < 2; ++i)
#pragma unroll
        for (int r = 0; r < 4; ++r) {
          int m = wave * 32 + i * 16 + quad * 4 + r;
          L[m][dd] = f2bf((acc[i][j][r] + bn) * scl);
        }
    }
    __syncthreads();
    const int m = tid & 127;
    const int hl = tid >> 7;
    const int M = m0 + m;
    const int b = M / WN;
    const int tok = M - b * WN;
    const int h = hh * 2 + hl;
    unsigned short (*L)[40] = hl ? Lh1 : Lh0;
    unsigned short* drow = dst + (((size_t)b * NH + h) * WN + tok) * HD;
#pragma unroll
    for (int t2 = 0; t2 < 4; ++t2) {
      int d0 = t2 * 8;
      *(short8*)&drow[d0] = *(const short8*)&L[m][d0];
    }
  }
}

// ---------------- fused attention: single streaming loop, no softmax max-sub.
// 512 threads (8 waves) per block: same 51KB LDS -> 2 blocks/CU = 16 waves/CU
// (vs 12 at 256 threads) for latency hiding. Key rows permuted at staging
// (key kk=8q+4e+r -> LDS row 16e+4q+r); lane (c,quad) holds scores for query
// q0+c, keys quad*8+{0..7} = the PV A-frag. bias+mask enters as the QK^T MFMA
// C-operand. exp unnormalized; 1/l in epilogue. NOTE: plain __launch_bounds__
// — a min-waves arg makes the allocator cap VGPRs and spill (r5: +29MB).
__global__ __launch_bounds__(512) void attn_kernel(
    const unsigned short* __restrict__ qb, const unsigned short* __restrict__ kb,
    const unsigned short* __restrict__ vb, const uint32_t* __restrict__ biasP,
    const uint32_t* __restrict__ maskP, unsigned short* __restrict__ ob) {
  __shared__ __align__(16) unsigned short Ks[352][40];  // [perm key row][d]
  __shared__ __align__(16) unsigned short Vt[HD][360];  // [d][key]
  const int h = blockIdx.x, b = blockIdx.y;
  const int wdx = b & (NWM - 1);
  const int tid = threadIdx.x;
  const int wave = tid >> 6, lane = tid & 63;
  const int quad = lane >> 4, c = lane & 15;
  const size_t base = ((size_t)b * NH + h) * (WN * HD);
  const unsigned short* q = qb + base;
  const unsigned short* k = kb + base;
  const unsigned short* v = vb + base;
  const uint32_t* bP = biasP + (size_t)h * BMSLICE;
  const uint32_t* mP = maskP + (size_t)wdx * BMSLICE;

  // stage K with permuted rows
  for (int t = tid; t < WN * 4; t += 512) {
    int r = t >> 2, ch = t & 3;
    int kk = r & 31;
    int row = (r & ~31) + 16 * ((kk >> 2) & 1) + 4 * (kk >> 3) + (kk & 3);
    *(short8*)&Ks[row][ch * 8] = *(const short8*)(k + r * HD + ch * 8);
  }
  for (int t = tid; t < 9 * 32; t += 512) {
    int kg = WN + (t >> 5);
    int kk = kg & 31;
    int row = (kg & ~31) + 16 * ((kk >> 2) & 1) + 4 * (kk >> 3) + (kk & 3);
    Ks[row][t & 31] = 0;
  }
  // stage V transposed, natural key order
  for (int t = tid; t < WN; t += 512) {
#pragma unroll
    for (int ch = 0; ch < 4; ++ch) {
      short8 vv = *(const short8*)(v + t * HD + ch * 8);
#pragma unroll
      for (int j = 0; j < 8; ++j) Vt[ch * 8 + j][t] = vv[j];
    }
  }
  for (int t = tid; t < 9 * 32; t += 512) {
    Vt[t & 31][WN + (t >> 5)] = 0;
  }
  __syncthreads();

  for (int qt = wave; qt < 22; qt += 8) {
    const int q0 = qt * 16;
    int qr = q0 + c; if (qr > WN - 1) qr = WN - 1;
    const short8 qf = *(const short8*)(q + qr * HD + quad * 8);
    const uint32_t* bRow = bP + (size_t)(quad * 4) * BMROW + q0 + c;
    const uint32_t* mRow = mP + (size_t)(quad * 4) * BMROW + q0 + c;

    f32x4 o0 = (f32x4){0.f, 0.f, 0.f, 0.f}, o1 = (f32x4){0.f, 0.f, 0.f, 0.f};
    float l = 0.f;
#pragma unroll
    for (int kc = 0; kc < 11; ++kc) {
      // C-operand = bias+mask for this lane's 8 keys
      f32x4 cc0, cc1;
#pragma unroll
      for (int r = 0; r < 4; ++r) {
        uint32_t bw = bRow[(kc * 16 + r) * BMROW];
        uint32_t mw = mRow[(kc * 16 + r) * BMROW];
        __half2 s2 = __hadd2(*(__half2*)&bw, *(__half2*)&mw);
        float2 f = __half22float2(s2);
        cc0[r] = f.x;
        cc1[r] = f.y;
      }
      const int k0 = kc * 32;
      short8 kf0 = *(const short8*)&Ks[k0 + c][quad * 8];
      short8 kf1 = *(const short8*)&Ks[k0 + 16 + c][quad * 8];
      f32x4 s0 = __builtin_amdgcn_mfma_f32_16x16x32_bf16(kf0, qf, cc0, 0, 0, 0);
      f32x4 s1 = __builtin_amdgcn_mfma_f32_16x16x32_bf16(kf1, qf, cc1, 0, 0, 0);
      // unnormalized exp (OOB keys carry -60000 -> exp==0)
      float p0 = __expf(s0[0]), p1 = __expf(s0[1]);
      float p2 = __expf(s0[2]), p3 = __expf(s0[3]);
      float p4 = __expf(s1[0]), p5 = __expf(s1[1]);
      float p6 = __expf(s1[2]), p7 = __expf(s1[3]);
      l += (p0 + p1 + p2 + p3) + (p4 + p5 + p6 + p7);
      union { short8 v8; uint32_t d[4]; } pf;
      pf.d[0] = pk2bf(p0, p1);
      pf.d[1] = pk2bf(p2, p3);
      pf.d[2] = pk2bf(p4, p5);
      pf.d[3] = pk2bf(p6, p7);
      short8 vf0 = *(const short8*)&Vt[c][k0 + quad * 8];
      short8 vf1 = *(const short8*)&Vt[16 + c][k0 + quad * 8];
      o0 = __builtin_amdgcn_mfma_f32_16x16x32_bf16(pf.v8, vf0, o0, 0, 0, 0);
      o1 = __builtin_amdgcn_mfma_f32_16x16x32_bf16(pf.v8, vf1, o1, 0, 0, 0);
    }
    l += __shfl_xor(l, 16);
    l += __shfl_xor(l, 32);

    // Epilogue: O rows m=quad*4+r are queries q0+m; l lives at lane c=m
#pragma unroll
    for (int r = 0; r < 4; ++r) {
      int n = q0 + quad * 4 + r;
      if (n < WN) {
        float lq = __shfl(l, quad * 4 + r, 16);
        float inv = 1.0f / lq;
        size_t orow = ((size_t)b * WN + n) * CD + h * HD;
        ob[orow + c] = f2bf(o0[r] * inv);
        ob[orow + 16 + c] = f2bf(o1[r] * inv);
      }
    }
  }
}

// ---------------- output projection: 64x192 tile (grid 686 for occupancy),
// fp32 out
__global__ __launch_bounds__(256) void proj_kernel(
    const unsigned short* __restrict__ ob, const unsigned short* __restrict__ wpb,
    const float* __restrict__ bvec, float* __restrict__ out) {
  __shared__ __align__(16) unsigned short Xs[64][40];
  __shared__ __align__(16) unsigned short Ws[192][40];
  const int tid = threadIdx.x;
  const int wave = tid >> 6, lane = tid & 63;
  const int quad = lane >> 4, c = lane & 15;
  const int m0 = blockIdx.x * 64;

  f32x4 acc[12];
#pragma unroll
  for (int j = 0; j < 12; ++j) acc[j] = (f32x4){0.f, 0.f, 0.f, 0.f};

  for (int kt = 0; kt < 6; ++kt) {
    const int k0 = kt * 32;
    {
      int r = tid >> 2, ch = tid & 3;
      *(short8*)&Xs[r][ch * 8] =
          *(const short8*)(ob + (size_t)(m0 + r) * CD + k0 + ch * 8);
    }
#pragma unroll
    for (int it = 0; it < 3; ++it) {
      int r = it * 64 + (tid >> 2), ch = tid & 3;
      *(short8*)&Ws[r][ch * 8] =
          *(const short8*)(wpb + (size_t)r * CD + k0 + ch * 8);
    }
    __syncthreads();
    short8 af = *(const short8*)&Xs[wave * 16 + c][quad * 8];
#pragma unroll
    for (int j = 0; j < 12; ++j) {
      short8 bfr = *(const short8*)&Ws[j * 16 + c][quad * 8];
      acc[j] = __builtin_amdgcn_mfma_f32_16x16x32_bf16(af, bfr, acc[j], 0, 0, 0);
    }
    __syncthreads();
  }

#pragma unroll
  for (int j = 0; j < 12; ++j) {
    int col = j * 16 + c;
    float bn = bvec[col];
#pragma unroll
    for (int r = 0; r < 4; ++r) {
      int m = m0 + wave * 16 + quad * 4 + r;
      out[(size_t)m * CD + col] = acc[j][r] + bn;
    }
  }
}

extern "C" void kernel_launch(void* const* d_in, const int* in_sizes, int n_in,
                              void* d_out, int out_size, void* d_ws, size_t ws_size,
                              hipStream_t stream) {
  const float* x      = (const float*)d_in[0];
  const float* mask   = (const float*)d_in[1];
  const float* qkv_w  = (const float*)d_in[2];
  const float* qkv_b  = (const float*)d_in[3];
  const float* proj_w = (const float*)d_in[4];
  const float* proj_b = (const float*)d_in[5];
  const float* rpb    = (const float*)d_in[6];
  const int*   rel    = (const int*)d_in[7];
  float* out = (float*)d_out;

  char* ws = (char*)d_ws;
  uint32_t* biasP = (uint32_t*)ws;                       // 6*61952*4  = 1,486,848
  size_t off = 1486848;
  uint32_t* maskP = (uint32_t*)(ws + off); off += 7929856;  // 32*61952*4
  unsigned short* qb = (unsigned short*)(ws + off); off += 16859136;
  unsigned short* kb = (unsigned short*)(ws + off); off += 16859136;
  unsigned short* vb = (unsigned short*)(ws + off); off += 16859136;
  unsigned short* obuf = (unsigned short*)(ws + off); off += 16859136;
  unsigned short* wqb = (unsigned short*)(ws + off); off += 221184;
  unsigned short* wpb = (unsigned short*)(ws + off); off += 73728;

  hipLaunchKernelGGL(prep_kernel, dim3(418 + 144), dim3(256), 0, stream,
                     qkv_w, proj_w, wqb, wpb, rel, rpb, mask, biasP, maskP);
  hipLaunchKernelGGL(qkv_kernel, dim3(343, 3), dim3(256), 0, stream,
                     x, wqb, qkv_b, qb, kb, vb);
  hipLaunchKernelGGL(attn_kernel, dim3(NH, NB), dim3(512), 0, stream,
                     qb, kb, vb, biasP, maskP, obuf);
  hipLaunchKernelGGL(proj_kernel, dim3(686), dim3(256), 0, stream,
                     obuf, wpb, proj_b, out);
}